// Round 1
// baseline (1101.352 us; speedup 1.0000x reference)
//
#include <hip/hip_runtime.h>
#include <hip/hip_bf16.h>
#include <math.h>

#define NTOK 4096   // B*L
#define DM   2048   // model dim
#define NE   8      // experts
#define BM   128
#define BK   32

using f32x4  = float __attribute__((ext_vector_type(4)));
using bf16x8 = __bf16 __attribute__((ext_vector_type(8)));
using u32x4  = unsigned int __attribute__((ext_vector_type(4)));

__device__ __forceinline__ unsigned short bf16bits(float f){
  unsigned u = __builtin_bit_cast(unsigned, f);
  return (unsigned short)((u + 0x7fffu + ((u >> 16) & 1u)) >> 16);  // RNE
}

__device__ __forceinline__ void load_lds16(const void* g, void* l){
  __builtin_amdgcn_global_load_lds(
      (const __attribute__((address_space(1))) unsigned int*)g,
      (__attribute__((address_space(3))) unsigned int*)l, 16, 0, 0);
}

// ---------------- router: rms-scale -> logits -> softmax -> top2 -> bucketize; also x->bf16
__global__ __launch_bounds__(256) void router_kernel(
    const float* __restrict__ x, const float* __restrict__ rs,
    const float* __restrict__ gw, const float* __restrict__ pes,
    unsigned short* __restrict__ xbf, int* __restrict__ cnt,
    int* __restrict__ toklist, float* __restrict__ slotw)
{
  const int wv = threadIdx.x >> 6, l = threadIdx.x & 63;
  const int n = blockIdx.x * 4 + wv;            // one wave per token
  const float* xr = x + (size_t)n * DM;
  unsigned short* xb = xbf + (size_t)n * DM;
  float ssq = 0.f;
  float lg[8] = {0,0,0,0,0,0,0,0};
  #pragma unroll
  for (int q = 0; q < 8; ++q){
    int c4 = l + 64 * q;                         // float4 chunk
    float4 v = ((const float4*)xr)[c4];
    float4 r = ((const float4*)rs)[c4];
    ssq += v.x*v.x + v.y*v.y + v.z*v.z + v.w*v.w;
    ushort4 o; o.x = bf16bits(v.x); o.y = bf16bits(v.y); o.z = bf16bits(v.z); o.w = bf16bits(v.w);
    ((ushort4*)xb)[c4] = o;
    float xs0 = v.x*r.x, xs1 = v.y*r.y, xs2 = v.z*r.z, xs3 = v.w*r.w;
    const float4* gp = (const float4*)(gw + (size_t)c4 * 32); // 4 rows x 8 experts
    float4 ga, gb;
    ga = gp[0]; gb = gp[1];
    lg[0]+=xs0*ga.x; lg[1]+=xs0*ga.y; lg[2]+=xs0*ga.z; lg[3]+=xs0*ga.w;
    lg[4]+=xs0*gb.x; lg[5]+=xs0*gb.y; lg[6]+=xs0*gb.z; lg[7]+=xs0*gb.w;
    ga = gp[2]; gb = gp[3];
    lg[0]+=xs1*ga.x; lg[1]+=xs1*ga.y; lg[2]+=xs1*ga.z; lg[3]+=xs1*ga.w;
    lg[4]+=xs1*gb.x; lg[5]+=xs1*gb.y; lg[6]+=xs1*gb.z; lg[7]+=xs1*gb.w;
    ga = gp[4]; gb = gp[5];
    lg[0]+=xs2*ga.x; lg[1]+=xs2*ga.y; lg[2]+=xs2*ga.z; lg[3]+=xs2*ga.w;
    lg[4]+=xs2*gb.x; lg[5]+=xs2*gb.y; lg[6]+=xs2*gb.z; lg[7]+=xs2*gb.w;
    ga = gp[6]; gb = gp[7];
    lg[0]+=xs3*ga.x; lg[1]+=xs3*ga.y; lg[2]+=xs3*ga.z; lg[3]+=xs3*ga.w;
    lg[4]+=xs3*gb.x; lg[5]+=xs3*gb.y; lg[6]+=xs3*gb.z; lg[7]+=xs3*gb.w;
  }
  #pragma unroll
  for (int off = 32; off; off >>= 1){
    ssq += __shfl_xor(ssq, off, 64);
    #pragma unroll
    for (int e2 = 0; e2 < 8; ++e2) lg[e2] += __shfl_xor(lg[e2], off, 64);
  }
  if (l == 0){
    float c = rsqrtf(ssq * (1.0f/DM) + 1e-6f) * 0.022097086912079608f; // rms * D^-0.5
    float mx = -1e30f;
    #pragma unroll
    for (int e2 = 0; e2 < 8; ++e2){ lg[e2] *= c; mx = fmaxf(mx, lg[e2]); }
    // top-2 (ties -> lower index, strict >)
    float l0 = lg[0]; int i0 = 0;
    #pragma unroll
    for (int e2 = 1; e2 < 8; ++e2) if (lg[e2] > l0){ l0 = lg[e2]; i0 = e2; }
    int i1 = (i0 == 0) ? 1 : 0; float l1 = lg[0] == l0 && i0 == 0 ? lg[1] : lg[0];
    l1 = (i0 == 0) ? lg[1] : lg[0];
    #pragma unroll
    for (int e2 = 0; e2 < 8; ++e2){ if (e2 != i0 && lg[e2] > l1){ l1 = lg[e2]; i1 = e2; } }
    float p0 = expf(l0 - mx), p1 = expf(l1 - mx);
    float sw = fmaxf(p0 + p1, 1e-12f);
    float w0 = p0 / sw, w1 = p1 / sw;
    int s0 = atomicAdd(&cnt[i0], 1);
    toklist[i0 * NTOK + s0] = n;
    slotw[i0 * NTOK + s0] = w0 * pes[i0];
    int s1 = atomicAdd(&cnt[i1], 1);
    toklist[i1 * NTOK + s1] = n;
    slotw[i1 * NTOK + s1] = w1 * pes[i1];
  }
}

__global__ void scan_kernel(const int* __restrict__ cnt, int* __restrict__ basep){
  if (threadIdx.x == 0){
    int a = 0;
    for (int e = 0; e < NE; ++e){ basep[e] = a; a += cnt[e]; }
  }
}

// ---------------- grouped GEMM. MODE 0: act[s,f] = gelu(x@Wg) * (x@Wu), bf16 out.
//                  MODE 1: out[tok] += w * (act @ Wd), fp32 atomic scatter.
// Block: 256 thr (4 waves, 2x2), tile 128 rows x (2 x 128 cols). 16x16x32 bf16 MFMA.
// LDS: linear 64B rows, 16B-granule XOR swizzle (pg = g ^ ((row>>1)&3)) -> ~2-way frag reads.
template<int MODE>
__global__ __launch_bounds__(256, 2) void moe_gemm(
    const unsigned short* __restrict__ Abuf,   // xbf (MODE0) / act (MODE1)
    const float* __restrict__ W,               // gate_up / down
    unsigned short* __restrict__ act,
    float* __restrict__ out,
    const int* __restrict__ cnt,
    const int* __restrict__ basep,
    const int* __restrict__ toklist,
    const float* __restrict__ slotw)
{
  const int e  = blockIdx.z;
  const int ce = cnt[e];
  const int m0 = blockIdx.y * BM;
  if (m0 >= ce) return;
  const int nb  = blockIdx.x;
  const int tid = threadIdx.x;
  const int l   = tid & 63;
  const int wv  = tid >> 6;
  const int wr  = wv >> 1, wc = wv & 1;
  const int baseE = basep[e];

  __shared__ unsigned short As[BM * BK];        // 8 KiB
  __shared__ unsigned short Bs[2][128 * BK];    // 16 KiB

  // A staging (global_load_lds, 2 chunks of 16B per thread). chunk ci = q*256+tid,
  // row = ci>>2, phys granule = ci&3, logical g = pg ^ ((row>>1)&3).
  const unsigned short* asrc0;
  const unsigned short* asrc1;
  {
    int row0 = tid >> 2, row1 = 64 + (tid >> 2);
    int gs = tid & 3;
    int g0 = gs ^ ((row0 >> 1) & 3);
    int g1 = gs ^ ((row1 >> 1) & 3);
    long r0src, r1src;
    if (MODE == 0){
      r0src = toklist[e * NTOK + min(m0 + row0, ce - 1)];
      r1src = toklist[e * NTOK + min(m0 + row1, ce - 1)];
    } else {
      r0src = baseE + min(m0 + row0, ce - 1);
      r1src = baseE + min(m0 + row1, ce - 1);
    }
    asrc0 = Abuf + (size_t)r0src * 2048 + g0 * 8;
    asrc1 = Abuf + (size_t)r1src * 2048 + g1 * 8;
  }
  unsigned short* adst0 = As + (wv * 64) * 8;         // wave-uniform LDS bases
  unsigned short* adst1 = As + (256 + wv * 64) * 8;

  // B staging mapping: th = col-half, ko = k-octet, n4 = 4-column group
  const int th = tid >> 7;
  const int tt = tid & 127;
  const int ko = tt & 3;
  const int n4 = (tt >> 2) * 4;
  const size_t wrow = (MODE == 0) ? 4096 : 2048;
  const int cb = (MODE == 0) ? (nb * 128 + th * 2048) : (nb * 256 + th * 128);
  const float* wbase = W + (size_t)e * 2048 * wrow + cb + n4;
  const bool odd = tid & 1;

  // frag read offsets (elements); swizzle constant across mi/ni since 16 ≡ 0 mod (granule period)
  const int arow = wr * 64 + (l & 15);
  const int aswz = (l >> 4) ^ ((arow >> 1) & 3);
  const int aoff = arow * BK + aswz * 8;
  const int bcol = wc * 64 + (l & 15);
  const int bswz = (l >> 4) ^ ((bcol >> 1) & 3);
  const int boff = bcol * BK + bswz * 8;

  f32x4 acc[2][4][4];
  #pragma unroll
  for (int t2 = 0; t2 < 2; ++t2)
    #pragma unroll
    for (int i = 0; i < 4; ++i)
      #pragma unroll
      for (int j = 0; j < 4; ++j)
        acc[t2][i][j] = (f32x4){0.f, 0.f, 0.f, 0.f};

  #pragma unroll 1
  for (int k0 = 0; k0 < 2048; k0 += BK){
    if (k0) __syncthreads();
    load_lds16(asrc0 + k0, adst0);
    load_lds16(asrc1 + k0, adst1);

    // B: gather 8 k's x 4 cols as fp32, convert+pack to bf16 k-pairs in registers
    unsigned p0[4], p1[4], p2[4], p3[4];
    {
      const float* wp = wbase + (size_t)(k0 + ko * 8) * wrow;
      #pragma unroll
      for (int q = 0; q < 8; ++q){
        float4 v = *(const float4*)(wp + (size_t)q * wrow);
        unsigned short b0 = bf16bits(v.x), b1 = bf16bits(v.y),
                       b2 = bf16bits(v.z), b3 = bf16bits(v.w);
        if ((q & 1) == 0){ p0[q>>1] = b0; p1[q>>1] = b1; p2[q>>1] = b2; p3[q>>1] = b3; }
        else { p0[q>>1] |= (unsigned)b0 << 16; p1[q>>1] |= (unsigned)b1 << 16;
               p2[q>>1] |= (unsigned)b2 << 16; p3[q>>1] |= (unsigned)b3 << 16; }
      }
    }
    {
      u32x4 c0 = {p0[0],p0[1],p0[2],p0[3]};
      u32x4 c1 = {p1[0],p1[1],p1[2],p1[3]};
      u32x4 c2 = {p2[0],p2[1],p2[2],p2[3]};
      u32x4 c3 = {p3[0],p3[1],p3[2],p3[3]};
      u32x4 wA = odd ? c1 : c0;
      u32x4 wB = odd ? c0 : c1;
      u32x4 wC = odd ? c3 : c2;
      u32x4 wD = odd ? c2 : c3;
      int nA = n4 + (int)odd;
      int nB = n4 + (1 ^ (int)odd);
      int nC = n4 + 2 + (int)odd;
      int nD = n4 + 2 + (1 ^ (int)odd);
      int pgA = ko ^ ((nA >> 1) & 3);
      int pgB = ko ^ ((nB >> 1) & 3);
      int pgC = ko ^ ((nC >> 1) & 3);
      int pgD = ko ^ ((nD >> 1) & 3);
      *(u32x4*)&Bs[th][nA * BK + pgA * 8] = wA;
      *(u32x4*)&Bs[th][nB * BK + pgB * 8] = wB;
      *(u32x4*)&Bs[th][nC * BK + pgC * 8] = wC;
      *(u32x4*)&Bs[th][nD * BK + pgD * 8] = wD;
    }
    __syncthreads();

    bf16x8 af[4];
    #pragma unroll
    for (int mi = 0; mi < 4; ++mi)
      af[mi] = *(const bf16x8*)&As[aoff + mi * 16 * BK];
    #pragma unroll
    for (int t2 = 0; t2 < 2; ++t2)
      #pragma unroll
      for (int ni = 0; ni < 4; ++ni){
        bf16x8 bfr = *(const bf16x8*)&Bs[t2][boff + ni * 16 * BK];
        #pragma unroll
        for (int mi = 0; mi < 4; ++mi)
          acc[t2][mi][ni] = __builtin_amdgcn_mfma_f32_16x16x32_bf16(
              af[mi], bfr, acc[t2][mi][ni], 0, 0, 0);
      }
  }

  const int rloc = (l >> 4) * 4;
  if (MODE == 0){
    const int fcol = nb * 128 + wc * 64 + (l & 15);
    #pragma unroll
    for (int mi = 0; mi < 4; ++mi){
      #pragma unroll
      for (int j = 0; j < 4; ++j){
        int s = m0 + wr * 64 + mi * 16 + rloc + j;
        if (s < ce){
          size_t rowb = (size_t)(baseE + s) * 2048 + fcol;
          #pragma unroll
          for (int ni = 0; ni < 4; ++ni){
            float g = acc[0][mi][ni][j];
            float u = acc[1][mi][ni][j];
            float a = 0.5f * g * (1.0f + erff(g * 0.70710678118654752f)) * u; // exact gelu * up
            act[rowb + ni * 16] = bf16bits(a);
          }
        }
      }
    }
  } else {
    #pragma unroll
    for (int mi = 0; mi < 4; ++mi){
      #pragma unroll
      for (int j = 0; j < 4; ++j){
        int s = m0 + wr * 64 + mi * 16 + rloc + j;
        if (s < ce){
          int tokn = toklist[e * NTOK + s];
          float wgt = slotw[e * NTOK + s];
          float* orow = out + (size_t)tokn * 2048;
          #pragma unroll
          for (int t2 = 0; t2 < 2; ++t2)
            #pragma unroll
            for (int ni = 0; ni < 4; ++ni){
              int col = nb * 256 + t2 * 128 + wc * 64 + ni * 16 + (l & 15);
              atomicAdd(&orow[col], wgt * acc[t2][mi][ni][j]);
            }
        }
      }
    }
  }
}

extern "C" void kernel_launch(void* const* d_in, const int* in_sizes, int n_in,
                              void* d_out, int out_size, void* d_ws, size_t ws_size,
                              hipStream_t stream)
{
  const float* x   = (const float*)d_in[0];
  const float* rs  = (const float*)d_in[1];
  const float* gw  = (const float*)d_in[2];
  const float* w1  = (const float*)d_in[3];
  const float* w2  = (const float*)d_in[4];
  const float* pes = (const float*)d_in[5];
  float* out = (float*)d_out;

  // workspace layout (~48.5 MiB): cnt | base | toklist | slotw | x_bf16 | act_bf16
  char* ws = (char*)d_ws;
  int*   cnt     = (int*)ws;
  int*   basep   = (int*)(ws + 64);
  int*   toklist = (int*)(ws + 256);
  float* slotw   = (float*)(ws + 256 + (size_t)NE * NTOK * 4);
  unsigned short* xbf = (unsigned short*)(ws + 256 + 2 * (size_t)NE * NTOK * 4);
  unsigned short* act = xbf + (size_t)NTOK * DM;

  hipMemsetAsync(d_out, 0, (size_t)out_size * sizeof(float), stream);
  hipMemsetAsync(cnt, 0, 64, stream);
  router_kernel<<<NTOK / 4, 256, 0, stream>>>(x, rs, gw, pes, xbf, cnt, toklist, slotw);
  scan_kernel<<<1, 64, 0, stream>>>(cnt, basep);
  moe_gemm<0><<<dim3(16, 32, NE), 256, 0, stream>>>(xbf, w1, act, out, cnt, basep, toklist, slotw);
  moe_gemm<1><<<dim3(8, 32, NE), 256, 0, stream>>>(act, w2, act, out, cnt, basep, toklist, slotw);
}

// Round 2
// 540.460 us; speedup vs baseline: 2.0378x; 2.0378x over previous
//
#include <hip/hip_runtime.h>
#include <hip/hip_bf16.h>
#include <math.h>

#define NTOK 4096   // B*L
#define DM   2048   // model dim
#define NE   8      // experts
#define BM   128
#define BK   64

using f32x4  = float __attribute__((ext_vector_type(4)));
using bf16x8 = __bf16 __attribute__((ext_vector_type(8)));
using u32x4  = unsigned int __attribute__((ext_vector_type(4)));

__device__ __forceinline__ unsigned short bf16bits(float f){
  unsigned u = __builtin_bit_cast(unsigned, f);
  return (unsigned short)((u + 0x7fffu + ((u >> 16) & 1u)) >> 16);  // RNE
}

__device__ __forceinline__ void load_lds16(const void* g, void* l){
  __builtin_amdgcn_global_load_lds(
      (const __attribute__((address_space(1))) unsigned int*)g,
      (__attribute__((address_space(3))) unsigned int*)l, 16, 0, 0);
}

// ---------------- router: rms-scale -> logits -> softmax -> top2 -> bucketize; also x->bf16
__global__ __launch_bounds__(256) void router_kernel(
    const float* __restrict__ x, const float* __restrict__ rs,
    const float* __restrict__ gw, const float* __restrict__ pes,
    unsigned short* __restrict__ xbf, int* __restrict__ cnt,
    int* __restrict__ toklist, float* __restrict__ slotw)
{
  const int wv = threadIdx.x >> 6, l = threadIdx.x & 63;
  const int n = blockIdx.x * 4 + wv;            // one wave per token
  const float* xr = x + (size_t)n * DM;
  unsigned short* xb = xbf + (size_t)n * DM;
  float ssq = 0.f;
  float lg[8] = {0,0,0,0,0,0,0,0};
  #pragma unroll
  for (int q = 0; q < 8; ++q){
    int c4 = l + 64 * q;                         // float4 chunk
    float4 v = ((const float4*)xr)[c4];
    float4 r = ((const float4*)rs)[c4];
    ssq += v.x*v.x + v.y*v.y + v.z*v.z + v.w*v.w;
    ushort4 o; o.x = bf16bits(v.x); o.y = bf16bits(v.y); o.z = bf16bits(v.z); o.w = bf16bits(v.w);
    ((ushort4*)xb)[c4] = o;
    float xs0 = v.x*r.x, xs1 = v.y*r.y, xs2 = v.z*r.z, xs3 = v.w*r.w;
    const float4* gp = (const float4*)(gw + (size_t)c4 * 32); // 4 rows x 8 experts
    float4 ga, gb;
    ga = gp[0]; gb = gp[1];
    lg[0]+=xs0*ga.x; lg[1]+=xs0*ga.y; lg[2]+=xs0*ga.z; lg[3]+=xs0*ga.w;
    lg[4]+=xs0*gb.x; lg[5]+=xs0*gb.y; lg[6]+=xs0*gb.z; lg[7]+=xs0*gb.w;
    ga = gp[2]; gb = gp[3];
    lg[0]+=xs1*ga.x; lg[1]+=xs1*ga.y; lg[2]+=xs1*ga.z; lg[3]+=xs1*ga.w;
    lg[4]+=xs1*gb.x; lg[5]+=xs1*gb.y; lg[6]+=xs1*gb.z; lg[7]+=xs1*gb.w;
    ga = gp[4]; gb = gp[5];
    lg[0]+=xs2*ga.x; lg[1]+=xs2*ga.y; lg[2]+=xs2*ga.z; lg[3]+=xs2*ga.w;
    lg[4]+=xs2*gb.x; lg[5]+=xs2*gb.y; lg[6]+=xs2*gb.z; lg[7]+=xs2*gb.w;
    ga = gp[6]; gb = gp[7];
    lg[0]+=xs3*ga.x; lg[1]+=xs3*ga.y; lg[2]+=xs3*ga.z; lg[3]+=xs3*ga.w;
    lg[4]+=xs3*gb.x; lg[5]+=xs3*gb.y; lg[6]+=xs3*gb.z; lg[7]+=xs3*gb.w;
  }
  #pragma unroll
  for (int off = 32; off; off >>= 1){
    ssq += __shfl_xor(ssq, off, 64);
    #pragma unroll
    for (int e2 = 0; e2 < 8; ++e2) lg[e2] += __shfl_xor(lg[e2], off, 64);
  }
  if (l == 0){
    float c = rsqrtf(ssq * (1.0f/DM) + 1e-6f) * 0.022097086912079608f; // rms * D^-0.5
    float mx = -1e30f;
    #pragma unroll
    for (int e2 = 0; e2 < 8; ++e2){ lg[e2] *= c; mx = fmaxf(mx, lg[e2]); }
    float l0 = lg[0]; int i0 = 0;
    #pragma unroll
    for (int e2 = 1; e2 < 8; ++e2) if (lg[e2] > l0){ l0 = lg[e2]; i0 = e2; }
    int i1 = (i0 == 0) ? 1 : 0; float l1 = (i0 == 0) ? lg[1] : lg[0];
    #pragma unroll
    for (int e2 = 0; e2 < 8; ++e2){ if (e2 != i0 && lg[e2] > l1){ l1 = lg[e2]; i1 = e2; } }
    float p0 = expf(l0 - mx), p1 = expf(l1 - mx);
    float sw = fmaxf(p0 + p1, 1e-12f);
    float w0 = p0 / sw, w1 = p1 / sw;
    int s0 = atomicAdd(&cnt[i0], 1);
    toklist[i0 * NTOK + s0] = n;
    slotw[i0 * NTOK + s0] = w0 * pes[i0];
    int s1 = atomicAdd(&cnt[i1], 1);
    toklist[i1 * NTOK + s1] = n;
    slotw[i1 * NTOK + s1] = w1 * pes[i1];
  }
}

__global__ void scan_kernel(const int* __restrict__ cnt, int* __restrict__ basep){
  if (threadIdx.x == 0){
    int a = 0;
    for (int e = 0; e < NE; ++e){ basep[e] = a; a += cnt[e]; }
  }
}

// ---------------- weight convert + transpose: W fp32 [2048 k][ncols n] -> Wt bf16 [ncols n][2048 k]
// grid (ncols/64, 32, EG); per-z expert offset. 64x64 tile via LDS.
__global__ __launch_bounds__(256) void conv_transpose_kernel(
    const float* __restrict__ W, unsigned short* __restrict__ Wt, int ncols)
{
  const int z = blockIdx.z;
  const float* src = W + (size_t)z * 2048 * ncols;
  unsigned short* dst = Wt + (size_t)z * ncols * 2048;
  const int n0 = blockIdx.x * 64, k0 = blockIdx.y * 64;
  __shared__ __align__(16) unsigned short t[64][72];   // [n][k], pad 8 -> conflict-free b128 reads
  const int tid = threadIdx.x;
  const int kl = tid >> 4;          // 0..15
  const int nl = (tid & 15) * 4;    // 0..60
  #pragma unroll
  for (int q = 0; q < 4; ++q){
    int k = kl + q * 16;
    float4 v = *(const float4*)(src + (size_t)(k0 + k) * ncols + n0 + nl);
    t[nl+0][k] = bf16bits(v.x);
    t[nl+1][k] = bf16bits(v.y);
    t[nl+2][k] = bf16bits(v.z);
    t[nl+3][k] = bf16bits(v.w);
  }
  __syncthreads();
  const int nr = tid >> 3;          // 0..31
  const int k8 = (tid & 7) * 8;
  #pragma unroll
  for (int q = 0; q < 2; ++q){
    int n = nr + q * 32;
    u32x4 v = *(const u32x4*)&t[n][k8];
    *(u32x4*)(dst + (size_t)(n0 + n) * 2048 + k0 + k8) = v;
  }
}

// ---------------- grouped GEMM, m97-style: global_load_lds(16B) both operands, BK=64,
// XOR-granule swizzle (phys_g = g ^ (row&7)) on linear LDS -> 2-way (free) b128 frag reads.
// MODE 0: act[s,f] = gelu(x@Wg) * (x@Wu); tile 128 x (128 gate + 128 up). MODE 1: scatter out.
template<int MODE>
__global__ __launch_bounds__(256, MODE ? 3 : 2) void moe_gemm(
    const unsigned short* __restrict__ Abuf,   // xbf (MODE0) / act (MODE1)
    const unsigned short* __restrict__ Wt,     // group base, bf16 [z][ncols][2048]
    unsigned short* __restrict__ act,
    float* __restrict__ out,
    const int* __restrict__ cnt,
    const int* __restrict__ basep,
    const int* __restrict__ toklist,
    const float* __restrict__ slotw,
    int e0)
{
  constexpr int NH = (MODE == 0) ? 2 : 1;
  constexpr int BCOLS = NH * 128;
  const int z = blockIdx.z;
  const int e = e0 + z;
  const int ce = cnt[e];
  const int m0 = blockIdx.y * BM;
  if (m0 >= ce) return;
  const int fb = blockIdx.x * 128;
  const int tid = threadIdx.x;
  const int l = tid & 63;
  const int wv = tid >> 6;
  const int wr = wv >> 1, wc = wv & 1;
  const int baseE = basep[e];
  const size_t ncols = (MODE == 0) ? 4096 : 2048;
  const unsigned short* Wz = Wt + (size_t)z * ncols * 2048;

  __shared__ __align__(16) unsigned short As[BM * BK];       // 16 KiB
  __shared__ __align__(16) unsigned short Bs[BCOLS * BK];    // 32 / 16 KiB

  // staging sources: chunk c = q*256+tid -> row = q*32 + (tid>>3), phys granule tid&7,
  // logical granule g = (tid&7) ^ (row&7); LDS dst linear (wave-uniform base + lane*16B)
  const unsigned short* asrc[4];
  #pragma unroll
  for (int q = 0; q < 4; ++q){
    int row = q * 32 + (tid >> 3);
    int g = (tid & 7) ^ (row & 7);
    long rs;
    if (MODE == 0) rs = toklist[e * NTOK + min(m0 + row, ce - 1)];
    else           rs = baseE + min(m0 + row, ce - 1);
    asrc[q] = Abuf + (size_t)rs * 2048 + g * 8;
  }
  const unsigned short* bsrc[NH * 4];
  #pragma unroll
  for (int q = 0; q < NH * 4; ++q){
    int col = q * 32 + (tid >> 3);
    int g = (tid & 7) ^ (col & 7);
    int n;
    if (MODE == 0) n = (col & 128) ? (2048 + fb + (col - 128)) : (fb + col);
    else           n = fb + col;
    bsrc[q] = Wz + (size_t)n * 2048 + g * 8;
  }

  f32x4 acc[NH][4][4];
  #pragma unroll
  for (int h = 0; h < NH; ++h)
    #pragma unroll
    for (int i = 0; i < 4; ++i)
      #pragma unroll
      for (int j = 0; j < 4; ++j)
        acc[h][i][j] = (f32x4){0.f, 0.f, 0.f, 0.f};

  const int aoff0 = (wr * 64 + (l & 15)) * BK;
  const int boff0 = (wc * 64 + (l & 15)) * BK;
  const int lsw = l & 7;
  const int lq = l >> 4;

  #pragma unroll 1
  for (int k0 = 0; k0 < 2048; k0 += BK){
    if (k0) __syncthreads();
    #pragma unroll
    for (int q = 0; q < 4; ++q)
      load_lds16(asrc[q] + k0, &As[q * 2048 + wv * 512]);
    #pragma unroll
    for (int q = 0; q < NH * 4; ++q)
      load_lds16(bsrc[q] + k0, &Bs[q * 2048 + wv * 512]);
    __syncthreads();
    #pragma unroll
    for (int kk = 0; kk < 2; ++kk){
      const int gsw = ((kk * 4 + lq) ^ lsw) * 8;
      bf16x8 af[4];
      #pragma unroll
      for (int mi = 0; mi < 4; ++mi)
        af[mi] = *(const bf16x8*)&As[aoff0 + mi * 16 * BK + gsw];
      #pragma unroll
      for (int h = 0; h < NH; ++h)
        #pragma unroll
        for (int ni = 0; ni < 4; ++ni){
          bf16x8 bfr = *(const bf16x8*)&Bs[boff0 + (h * 128 + ni * 16) * BK + gsw];
          #pragma unroll
          for (int mi = 0; mi < 4; ++mi)
            acc[h][mi][ni] = __builtin_amdgcn_mfma_f32_16x16x32_bf16(
                af[mi], bfr, acc[h][mi][ni], 0, 0, 0);
        }
    }
  }

  if (MODE == 0){
    const int fcol = fb + wc * 64 + (l & 15);
    #pragma unroll
    for (int mi = 0; mi < 4; ++mi)
      #pragma unroll
      for (int j = 0; j < 4; ++j){
        int s = m0 + wr * 64 + mi * 16 + lq * 4 + j;
        if (s < ce){
          size_t rowb = (size_t)(baseE + s) * 2048 + fcol;
          #pragma unroll
          for (int ni = 0; ni < 4; ++ni){
            float g = acc[0][mi][ni][j];
            float u = acc[1][mi][ni][j];
            float a = 0.5f * g * (1.0f + erff(g * 0.70710678118654752f)) * u; // exact gelu * up
            act[rowb + ni * 16] = bf16bits(a);
          }
        }
      }
  } else {
    #pragma unroll
    for (int mi = 0; mi < 4; ++mi)
      #pragma unroll
      for (int j = 0; j < 4; ++j){
        int s = m0 + wr * 64 + mi * 16 + lq * 4 + j;
        if (s < ce){
          int tokn = toklist[e * NTOK + s];
          float wgt = slotw[e * NTOK + s];
          float* orow = out + (size_t)tokn * 2048 + fb + wc * 64 + (l & 15);
          #pragma unroll
          for (int ni = 0; ni < 4; ++ni)
            atomicAdd(&orow[ni * 16], wgt * acc[0][mi][ni][j]);
        }
      }
  }
}

extern "C" void kernel_launch(void* const* d_in, const int* in_sizes, int n_in,
                              void* d_out, int out_size, void* d_ws, size_t ws_size,
                              hipStream_t stream)
{
  const float* x   = (const float*)d_in[0];
  const float* rs  = (const float*)d_in[1];
  const float* gw  = (const float*)d_in[2];
  const float* w1  = (const float*)d_in[3];
  const float* w2  = (const float*)d_in[4];
  const float* pes = (const float*)d_in[5];
  float* out = (float*)d_out;

  // ws: cnt | base | toklist | slotw | x_bf16 (16MB) | act_bf16 (32MB) | Wt region (EG*16MB)
  char* ws = (char*)d_ws;
  int*   cnt     = (int*)ws;
  int*   basep   = (int*)(ws + 64);
  int*   toklist = (int*)(ws + 256);
  float* slotw   = (float*)(ws + 256 + (size_t)NE * NTOK * 4);
  unsigned short* xbf = (unsigned short*)(ws + 256 + 2 * (size_t)NE * NTOK * 4);
  unsigned short* act = xbf + (size_t)NTOK * DM;
  unsigned short* wtb = act + (size_t)2 * NTOK * DM;

  const size_t fixed = (size_t)((char*)wtb - ws);
  const size_t per_e = (size_t)4096 * 2048 * 2;   // 16 MiB (W1 per expert; W2 uses half)
  int EG = NE;
  while (EG > 1 && fixed + (size_t)EG * per_e > ws_size) EG >>= 1;

  hipMemsetAsync(d_out, 0, (size_t)out_size * sizeof(float), stream);
  hipMemsetAsync(cnt, 0, 64, stream);
  router_kernel<<<NTOK / 4, 256, 0, stream>>>(x, rs, gw, pes, xbf, cnt, toklist, slotw);
  scan_kernel<<<1, 64, 0, stream>>>(cnt, basep);

  for (int g = 0; g < NE; g += EG){
    conv_transpose_kernel<<<dim3(64, 32, EG), 256, 0, stream>>>(
        w1 + (size_t)g * 2048 * 4096, wtb, 4096);
    moe_gemm<0><<<dim3(16, 32, EG), 256, 0, stream>>>(
        xbf, wtb, act, out, cnt, basep, toklist, slotw, g);
  }
  for (int g = 0; g < NE; g += EG){
    conv_transpose_kernel<<<dim3(32, 32, EG), 256, 0, stream>>>(
        w2 + (size_t)g * 2048 * 2048, wtb, 2048);
    moe_gemm<1><<<dim3(16, 32, EG), 256, 0, stream>>>(
        act, wtb, act, out, cnt, basep, toklist, slotw, g);
  }
}